// Round 7
// baseline (192.834 us; speedup 1.0000x reference)
//
#include <hip/hip_runtime.h>
#include <hip/hip_bf16.h>

// PAM module R7: q/k/v 1x1 projections -> bf16 MFMA attention -> gamma*out + x.
// R6 post-mortem: 2.1 GB of L2 reads (21 TB/s, ~62% of per-XCD ceiling) + 2 waves/
// SIMD serial chain -> 30% MFMA. R7: grid 512 (64-row strips), 8 waves = 2 m-half
// x 4 n-quarter => K/V reuse = 2 through LDS; K/V DMA'd (global_load_lds 16B) into
// double-buffered 64-m subtiles, ONE barrier per subiter with DMA issued before
// compute (drain covered by compute, not exposed). Per-wave regs: qf16 + oacc32
// (AGPR) => 4 waves/SIMD, 2 blocks/CU. P stays in registers via bpermute.
//
// Workspace layouts (bf16, chunk = 64 lanes x 16B = 1KB, frag-major, unchanged):
//   qf_ws[b][strip32][ni2][kc4][lane]         8MB
//   kt   [b][tile128][mb8][kc4][lane]         8MB
//   vt   [b][tile128]{cb,wq,l16}              8MB

typedef __bf16 v8bf __attribute__((ext_vector_type(8)));
typedef float  v4f  __attribute__((ext_vector_type(4)));
typedef __attribute__((address_space(3))) void       lds_v;
typedef const __attribute__((address_space(1))) void gbl_v;

#define B_ 8
#define C_ 128
#define N_ 4096

static __device__ __forceinline__ unsigned short f2bf_rne(float f) {
    union { float f; unsigned u; } v; v.f = f;
    return (unsigned short)((v.u + 0x7fffu + ((v.u >> 16) & 1u)) >> 16);
}
static __device__ __forceinline__ unsigned fbits(float f) {
    union { float f; unsigned u; } v; v.f = f; return v.u;
}

// ---------------------------------------------------------------------------
// Kernel 1: unchanged from R4/R6 (proven; isolating the attn variable).
// ---------------------------------------------------------------------------
__global__ __launch_bounds__(256, 2) void proj_kernel(
    const float* __restrict__ x,
    const float* __restrict__ dw_q, const float* __restrict__ pw_q,
    const float* __restrict__ dw_k, const float* __restrict__ pw_k,
    const float* __restrict__ dw_v, const float* __restrict__ pw_v,
    unsigned short* __restrict__ qf_ws, unsigned short* __restrict__ kt,
    unsigned short* __restrict__ vt)
{
    __shared__ unsigned short xT[128 * 136];
    __shared__ unsigned short Ws[128 * 136];

    const int bid = blockIdx.x;
    const int bb  = bid & 7;
    const int t   = (bid >> 3) & 31;
    const int pp  = bid >> 8;
    const int n0  = t * 128;
    const int tid = threadIdx.x;
    const int w    = tid >> 6;
    const int lane = tid & 63;
    const int quad = lane >> 4;
    const int l16  = lane & 15;

    #pragma unroll
    for (int k = 0; k < 16; ++k) {
        const int idx = tid + k * 256;
        const int c  = idx >> 5;
        const int nq = idx & 31;
        float4 f = *(const float4*)(x + ((size_t)(bb * C_ + c)) * N_ + n0 + nq * 4);
        xT[(nq * 4 + 0) * 136 + c] = f2bf_rne(f.x);
        xT[(nq * 4 + 1) * 136 + c] = f2bf_rne(f.y);
        xT[(nq * 4 + 2) * 136 + c] = f2bf_rne(f.z);
        xT[(nq * 4 + 3) * 136 + c] = f2bf_rne(f.w);
    }
    const float* pw = (pp == 0) ? pw_q : (pp == 1) ? pw_k : pw_v;
    const float* dw = (pp == 0) ? dw_q : (pp == 1) ? dw_k : dw_v;
    #pragma unroll
    for (int k = 0; k < 16; ++k) {
        const int idx = tid + k * 256;
        const int o  = idx >> 5;
        const int c4 = (idx & 31) * 4;
        float4 p4 = *(const float4*)(pw + o * 128 + c4);
        float4 d4 = *(const float4*)(dw + c4);
        unsigned lo = (unsigned)f2bf_rne(p4.x * d4.x) | ((unsigned)f2bf_rne(p4.y * d4.y) << 16);
        unsigned hi = (unsigned)f2bf_rne(p4.z * d4.z) | ((unsigned)f2bf_rne(p4.w * d4.w) << 16);
        *(unsigned long long*)&Ws[o * 136 + c4] =
            (unsigned long long)lo | ((unsigned long long)hi << 32);
    }
    __syncthreads();

    const unsigned short* As = (pp < 2) ? xT : Ws;
    const unsigned short* Bs = (pp < 2) ? Ws : xT;

    v4f acc[2][8];
    #pragma unroll
    for (int i = 0; i < 2; ++i)
        #pragma unroll
        for (int j = 0; j < 8; ++j)
            acc[i][j] = (v4f){0.f, 0.f, 0.f, 0.f};

    #pragma unroll
    for (int kc = 0; kc < 4; ++kc) {
        v8bf av[2];
        #pragma unroll
        for (int i = 0; i < 2; ++i)
            av[i] = *(const v8bf*)&As[(w * 32 + i * 16 + l16) * 136 + kc * 32 + quad * 8];
        #pragma unroll
        for (int cb = 0; cb < 8; ++cb) {
            v8bf bv = *(const v8bf*)&Bs[(cb * 16 + l16) * 136 + kc * 32 + quad * 8];
            acc[0][cb] = __builtin_amdgcn_mfma_f32_16x16x32_bf16(av[0], bv, acc[0][cb], 0, 0, 0);
            acc[1][cb] = __builtin_amdgcn_mfma_f32_16x16x32_bf16(av[1], bv, acc[1][cb], 0, 0, 0);
        }
    }
    __syncthreads();

    unsigned short* sc = Ws;
    #pragma unroll
    for (int mi = 0; mi < 2; ++mi)
        #pragma unroll
        for (int cb = 0; cb < 8; ++cb)
            #pragma unroll
            for (int r = 0; r < 4; ++r)
                sc[(w * 32 + mi * 16 + quad * 4 + r) * 136 + cb * 16 + l16] =
                    f2bf_rne(acc[mi][cb][r]);
    __syncthreads();

    if (pp == 0) {
        unsigned short* dst = qf_ws + ((size_t)(bb * 64 + t * 2)) * 8192;
        #pragma unroll
        for (int p = 0; p < 8; ++p) {
            const int g     = p * 4 + w;
            const int strip = g >> 4, ni = (g >> 2) & 3, kc = g & 3;
            *(uint4*)(dst + ((size_t)g * 64 + lane) * 8) =
                *(const uint4*)&sc[(strip * 64 + ni * 16 + l16) * 136 + kc * 32 + quad * 8];
        }
    } else if (pp == 1) {
        unsigned short* dst = kt + ((size_t)(bb * 32 + t)) * 16384;
        #pragma unroll
        for (int p = 0; p < 8; ++p) {
            const int g  = p * 4 + w;
            const int mb = g >> 2, kc = g & 3;
            *(uint4*)(dst + ((size_t)g * 64 + lane) * 8) =
                *(const uint4*)&sc[(mb * 16 + l16) * 136 + kc * 32 + quad * 8];
        }
    } else {
        unsigned short* dst = vt + ((size_t)(bb * 32 + t)) * 16384;
        #pragma unroll
        for (int p = 0; p < 8; ++p) {
            const int d  = p * 256 + tid;
            const int cb = d >> 8, wq = (d >> 4) & 15, l = d & 15;
            *(uint4*)(dst + (size_t)d * 8) =
                *(const uint4*)&sc[(cb * 16 + l) * 136 + wq * 8];
        }
    }
}

// ---------------------------------------------------------------------------
// Kernel 2: attention. grid 512 = (b = bid&7, 64-row n-strip = bid>>3).
// 512 thr / 8 waves: m-half (w&1) x n-quarter (w>>1). 64 subiters of 64 m:
//   sync; DMA(next subtile -> other buf); compute(this buf).
// DMA in flight during compute => the barrier's vmcnt drain is covered.
// ---------------------------------------------------------------------------
__global__ __launch_bounds__(512, 4) void attn_kernel(
    const unsigned short* __restrict__ qf_ws, const unsigned short* __restrict__ kt,
    const unsigned short* __restrict__ vt, const float* __restrict__ x,
    const float* __restrict__ gamma, float* __restrict__ out)
{
    __shared__ __align__(16) unsigned char smem[65536]; // kbuf[2]16K | vbuf[2]16K; red overlays
    __shared__ float l_s[2][64];

    const int bid = blockIdx.x;
    const int bb  = bid & 7;
    const int s   = bid >> 3;        // 64-row n-strip 0..63
    const int n0  = s * 64;
    const int tid = threadIdx.x;
    const int w    = tid >> 6;       // 8 waves: m-half = w&1, n-quarter = w>>1
    const int lane = tid & 63;
    const int quad = lane >> 4;
    const int l16  = lane & 15;
    const int mh   = w & 1;          // m-half within 64-m subtile
    const int nq   = w >> 1;         // n-quarter 0..3

    // ---- Q fragments (n=16 window), iteration-invariant: 16 VGPR
    v8bf qf[4];
    {
        const unsigned short* qb = qf_ws +
            ((size_t)(bb * 128 + s * 2 + (w >> 2))) * 4096;
        const int ni = (w >> 1) & 1;
        #pragma unroll
        for (int kc = 0; kc < 4; ++kc)
            qf[kc] = *(const v8bf*)(qb + ((size_t)((ni * 4 + kc) * 64 + lane)) * 8);
    }

    v4f oacc[8];   // 32 regs (AGPR): partial O over this wave's m-half subsets
    #pragma unroll
    for (int i = 0; i < 8; ++i) oacc[i] = (v4f){0.f, 0.f, 0.f, 0.f};
    float lpart = 0.f;

    const int la = ((((quad & 1) << 1) << 4) + l16) << 2;  // bpermute byte idx
    const int lb = la + 64;

    const unsigned short* kb0 = kt + (size_t)bb * 524288;  // batch K base (elems)
    const unsigned short* vb0 = vt + (size_t)bb * 524288;

    unsigned short* kbuf = (unsigned short*)smem;           // [2][8192] elems
    unsigned short* vbuf = (unsigned short*)(smem + 32768); // [2][8192] elems

    // ---- prologue: DMA subtile 0 into buf 0
    {
        #pragma unroll
        for (int i = 0; i < 2; ++i) {
            const int u = i * 512 + tid;
            __builtin_amdgcn_global_load_lds((gbl_v*)(kb0 + (size_t)u * 8),
                                             (lds_v*)(kbuf + u * 8), 16, 0, 0);
        }
        #pragma unroll
        for (int i = 0; i < 2; ++i) {
            const int u  = i * 512 + tid;
            const int cb = u >> 7, wr = (u >> 4) & 7, l = u & 15;
            __builtin_amdgcn_global_load_lds(
                (gbl_v*)(vb0 + cb * 2048 + wr * 128 + l * 8),
                (lds_v*)(vbuf + u * 8), 16, 0, 0);
        }
    }

    for (int si = 0; si < 64; ++si) {
        __syncthreads();   // buf[si&1] ready; prior readers of buf[(si+1)&1] done

        // ---- DMA next subtile into the other buffer (in flight during compute)
        if (si < 63) {
            const int sj = si + 1;
            const int p  = sj & 1;
            const unsigned short* ks = kb0 + (size_t)sj * 8192;
            const unsigned short* vs = vb0 + (size_t)(sj >> 1) * 16384 + (sj & 1) * 1024;
            #pragma unroll
            for (int i = 0; i < 2; ++i) {
                const int u = i * 512 + tid;
                __builtin_amdgcn_global_load_lds((gbl_v*)(ks + (size_t)u * 8),
                                                 (lds_v*)(kbuf + p * 8192 + u * 8), 16, 0, 0);
            }
            #pragma unroll
            for (int i = 0; i < 2; ++i) {
                const int u  = i * 512 + tid;
                const int cb = u >> 7, wr = (u >> 4) & 7, l = u & 15;
                __builtin_amdgcn_global_load_lds(
                    (gbl_v*)(vs + cb * 2048 + wr * 128 + l * 8),
                    (lds_v*)(vbuf + p * 8192 + u * 8), 16, 0, 0);
            }
        }

        // ---- compute on buf[si&1]
        const unsigned short* kp = kbuf + (si & 1) * 8192;
        const unsigned short* vp = vbuf + (si & 1) * 8192;

        // S^T: wave's 32 m x 16 n
        v4f sacc[2];
        sacc[0] = (v4f){0.f, 0.f, 0.f, 0.f};
        sacc[1] = (v4f){0.f, 0.f, 0.f, 0.f};
        #pragma unroll
        for (int mi = 0; mi < 2; ++mi)
            #pragma unroll
            for (int kc = 0; kc < 4; ++kc) {
                v8bf a = *(const v8bf*)(kp + (((mh * 2 + mi) * 4 + kc) * 64 + lane) * 8);
                sacc[mi] = __builtin_amdgcn_mfma_f32_16x16x32_bf16(a, qf[kc], sacc[mi], 0, 0, 0);
            }

        // exp + pack
        unsigned pk0[2], pk1[2];
        #pragma unroll
        for (int mi = 0; mi < 2; ++mi) {
            float e0 = __expf(sacc[mi][0]), e1 = __expf(sacc[mi][1]);
            float e2 = __expf(sacc[mi][2]), e3 = __expf(sacc[mi][3]);
            lpart += (e0 + e1) + (e2 + e3);
            pk0[mi] = __builtin_amdgcn_perm(fbits(e1), fbits(e0), 0x07060302);
            pk1[mi] = __builtin_amdgcn_perm(fbits(e3), fbits(e2), 0x07060302);
        }

        // C-layout -> B-frag via bpermute (R3/R6-proven mapping, m-extent 32)
        v8bf pf;
        {
            unsigned sLo = (quad < 2) ? pk0[0] : pk0[1];
            unsigned sHi = (quad < 2) ? pk1[0] : pk1[1];
            union { unsigned u[4]; v8bf v; } pu;
            pu.u[0] = (unsigned)__builtin_amdgcn_ds_bpermute(la, (int)sLo);
            pu.u[1] = (unsigned)__builtin_amdgcn_ds_bpermute(la, (int)sHi);
            pu.u[2] = (unsigned)__builtin_amdgcn_ds_bpermute(lb, (int)sLo);
            pu.u[3] = (unsigned)__builtin_amdgcn_ds_bpermute(lb, (int)sHi);
            pf = pu.v;
        }

        // O[c][n] += V * P  (K-dim = wave's 32 m)
        #pragma unroll
        for (int cb = 0; cb < 8; ++cb) {
            v8bf vv = *(const v8bf*)(vp + cb * 1024 + (mh * 4 + quad) * 128 + l16 * 8);
            oacc[cb] = __builtin_amdgcn_mfma_f32_16x16x32_bf16(vv, pf, oacc[cb], 0, 0, 0);
        }
    }

    // ---- softmax denominators: per-wave partial over its m-half
    {
        float r = lpart;
        r += __shfl_xor(r, 16);
        r += __shfl_xor(r, 32);
        if (lane < 16) l_s[mh][nq * 16 + lane] = r;
    }
    __syncthreads();   // main loop fully done; smem reusable

    // ---- O reduction across the 2 m-half waves per n-quarter: red[64][132]
    float* red = (float*)smem;
    #pragma unroll
    for (int ph = 0; ph < 2; ++ph) {
        if (mh == ph) {
            #pragma unroll
            for (int cb = 0; cb < 8; ++cb) {
                float* p = &red[(nq * 16 + l16) * 132 + cb * 16 + quad * 4];
                if (ph == 0) *(v4f*)p = oacc[cb];
                else {
                    v4f tv = *(const v4f*)p;
                    tv += oacc[cb];
                    *(v4f*)p = tv;
                }
            }
        }
        __syncthreads();
    }

    // ---- epilogue: out = gamma * O / l + x   (n = tid&63, coalesced)
    const float g = gamma[0];
    const int   n = tid & 63;
    const int  cg = tid >> 6;        // 0..7
    const float li = 1.0f / (l_s[0][n] + l_s[1][n]);
    #pragma unroll
    for (int j = 0; j < 16; ++j) {
        const int c = cg * 16 + j;
        const size_t idx = ((size_t)(bb * C_ + c)) * N_ + n0 + n;
        out[idx] = g * red[n * 132 + c] * li + x[idx];
    }
}

// ---------------------------------------------------------------------------
extern "C" void kernel_launch(void* const* d_in, const int* in_sizes, int n_in,
                              void* d_out, int out_size, void* d_ws, size_t ws_size,
                              hipStream_t stream)
{
    (void)in_sizes; (void)n_in; (void)out_size; (void)ws_size;
    const float* x     = (const float*)d_in[0];
    const float* dw_q  = (const float*)d_in[1];
    const float* pw_q  = (const float*)d_in[2];
    const float* dw_k  = (const float*)d_in[3];
    const float* pw_k  = (const float*)d_in[4];
    const float* dw_v  = (const float*)d_in[5];
    const float* pw_v  = (const float*)d_in[6];
    const float* gamma = (const float*)d_in[7];
    float* out = (float*)d_out;

    unsigned short* qf_ws = (unsigned short*)d_ws;                  // 8 MB
    unsigned short* kt    = qf_ws + (size_t)B_ * N_ * C_;           // 8 MB
    unsigned short* vt    = kt    + (size_t)B_ * N_ * C_;           // 8 MB

    proj_kernel<<<dim3(768), dim3(256), 0, stream>>>(
        x, dw_q, pw_q, dw_k, pw_k, dw_v, pw_v, qf_ws, kt, vt);
    attn_kernel<<<dim3(512), dim3(512), 0, stream>>>(
        qf_ws, kt, vt, x, gamma, out);
}

// Round 8
// 190.084 us; speedup vs baseline: 1.0145x; 1.0145x over previous
//
#include <hip/hip_runtime.h>
#include <hip/hip_bf16.h>

// PAM module R8: q/k/v 1x1 projections -> bf16 MFMA attention -> gamma*out + x.
// R7 post-mortem: LDS-pipe bound (4.19 GB of b128 reads, 1:1 read:MFMA). R8:
// W=2 (n=32/wave) halves operand traffic to 2.1 GB and SPLITS it across pipes:
// K through double-buffered LDS DMA, V through L2->register ping-pong (loads
// issued right after each barrier, a full subiter in flight). grid 256 (1 block/
// CU, batch-per-XCD L2 residency), 512 thr / 8 waves = 2 m-half x 4 n-quarter.
// Proj: ONE pass per (b,t): x read+converted once, 3 weight GEMMs (was 3x).
//
// Workspace (bf16, chunk = 64 lanes x 16B = 1KB, frag-major, layouts unchanged):
//   qf_ws[b][strip32][ni2][kc4][lane]         8MB
//   kt   [b][tile128][mb8][kc4][lane]         8MB
//   vt   [b][tile128]{cb8,wq16,l16}           8MB

typedef __bf16 v8bf __attribute__((ext_vector_type(8)));
typedef float  v4f  __attribute__((ext_vector_type(4)));
typedef __attribute__((address_space(3))) void       lds_v;
typedef const __attribute__((address_space(1))) void gbl_v;

#define B_ 8
#define C_ 128
#define N_ 4096

static __device__ __forceinline__ unsigned short f2bf_rne(float f) {
    union { float f; unsigned u; } v; v.f = f;
    return (unsigned short)((v.u + 0x7fffu + ((v.u >> 16) & 1u)) >> 16);
}
static __device__ __forceinline__ unsigned fbits(float f) {
    union { float f; unsigned u; } v; v.f = f; return v.u;
}

// ---------------------------------------------------------------------------
// Kernel 1: one block per (b, tile). 256 thr / 4 waves. x staged+converted ONCE,
// then 3 weight GEMMs (q,k,v) reusing xT. Store machinery identical to R4-R7.
// ---------------------------------------------------------------------------
__global__ __launch_bounds__(256, 2) void proj_kernel(
    const float* __restrict__ x,
    const float* __restrict__ dw_q, const float* __restrict__ pw_q,
    const float* __restrict__ dw_k, const float* __restrict__ pw_k,
    const float* __restrict__ dw_v, const float* __restrict__ pw_v,
    unsigned short* __restrict__ qf_ws, unsigned short* __restrict__ kt,
    unsigned short* __restrict__ vt)
{
    __shared__ unsigned short xT[128 * 136];  // xT[n][c] -- persists across pp
    __shared__ unsigned short Ws[128 * 136];  // W[o][c]; reused as store scratch

    const int bid = blockIdx.x;
    const int bb  = bid & 7;
    const int t   = bid >> 3;            // 0..31
    const int n0  = t * 128;
    const int tid = threadIdx.x;
    const int w    = tid >> 6;
    const int lane = tid & 63;
    const int quad = lane >> 4;
    const int l16  = lane & 15;

    // ---- stage xT[n][c] once (transpose + cvt bf16)
    #pragma unroll
    for (int k = 0; k < 16; ++k) {
        const int idx = tid + k * 256;
        const int c  = idx >> 5;
        const int nq = idx & 31;
        float4 f = *(const float4*)(x + ((size_t)(bb * C_ + c)) * N_ + n0 + nq * 4);
        xT[(nq * 4 + 0) * 136 + c] = f2bf_rne(f.x);
        xT[(nq * 4 + 1) * 136 + c] = f2bf_rne(f.y);
        xT[(nq * 4 + 2) * 136 + c] = f2bf_rne(f.z);
        xT[(nq * 4 + 3) * 136 + c] = f2bf_rne(f.w);
    }

    for (int pp = 0; pp < 3; ++pp) {
        __syncthreads();   // xT ready (pp=0) / prev copyout of Ws-scratch done

        const float* pw = (pp == 0) ? pw_q : (pp == 1) ? pw_k : pw_v;
        const float* dw = (pp == 0) ? dw_q : (pp == 1) ? dw_k : dw_v;
        #pragma unroll
        for (int k = 0; k < 16; ++k) {
            const int idx = tid + k * 256;
            const int o  = idx >> 5;
            const int c4 = (idx & 31) * 4;
            float4 p4 = *(const float4*)(pw + o * 128 + c4);
            float4 d4 = *(const float4*)(dw + c4);
            unsigned lo = (unsigned)f2bf_rne(p4.x * d4.x) | ((unsigned)f2bf_rne(p4.y * d4.y) << 16);
            unsigned hi = (unsigned)f2bf_rne(p4.z * d4.z) | ((unsigned)f2bf_rne(p4.w * d4.w) << 16);
            *(unsigned long long*)&Ws[o * 136 + c4] =
                (unsigned long long)lo | ((unsigned long long)hi << 32);
        }
        __syncthreads();

        const unsigned short* As = (pp < 2) ? xT : Ws;
        const unsigned short* Bs = (pp < 2) ? Ws : xT;

        v4f acc[2][8];
        #pragma unroll
        for (int i = 0; i < 2; ++i)
            #pragma unroll
            for (int j = 0; j < 8; ++j)
                acc[i][j] = (v4f){0.f, 0.f, 0.f, 0.f};

        #pragma unroll
        for (int kc = 0; kc < 4; ++kc) {
            v8bf av[2];
            #pragma unroll
            for (int i = 0; i < 2; ++i)
                av[i] = *(const v8bf*)&As[(w * 32 + i * 16 + l16) * 136 + kc * 32 + quad * 8];
            #pragma unroll
            for (int cb = 0; cb < 8; ++cb) {
                v8bf bv = *(const v8bf*)&Bs[(cb * 16 + l16) * 136 + kc * 32 + quad * 8];
                acc[0][cb] = __builtin_amdgcn_mfma_f32_16x16x32_bf16(av[0], bv, acc[0][cb], 0, 0, 0);
                acc[1][cb] = __builtin_amdgcn_mfma_f32_16x16x32_bf16(av[1], bv, acc[1][cb], 0, 0, 0);
            }
        }
        __syncthreads();   // done reading Ws; becomes scratch

        unsigned short* sc = Ws;
        #pragma unroll
        for (int mi = 0; mi < 2; ++mi)
            #pragma unroll
            for (int cb = 0; cb < 8; ++cb)
                #pragma unroll
                for (int r = 0; r < 4; ++r)
                    sc[(w * 32 + mi * 16 + quad * 4 + r) * 136 + cb * 16 + l16] =
                        f2bf_rne(acc[mi][cb][r]);
        __syncthreads();

        if (pp == 0) {
            unsigned short* dst = qf_ws + ((size_t)(bb * 64 + t * 2)) * 8192;
            #pragma unroll
            for (int pi = 0; pi < 8; ++pi) {
                const int g     = pi * 4 + w;
                const int strip = g >> 4, ni = (g >> 2) & 3, kc = g & 3;
                *(uint4*)(dst + ((size_t)g * 64 + lane) * 8) =
                    *(const uint4*)&sc[(strip * 64 + ni * 16 + l16) * 136 + kc * 32 + quad * 8];
            }
        } else if (pp == 1) {
            unsigned short* dst = kt + ((size_t)(bb * 32 + t)) * 16384;
            #pragma unroll
            for (int pi = 0; pi < 8; ++pi) {
                const int g  = pi * 4 + w;
                const int mb = g >> 2, kc = g & 3;
                *(uint4*)(dst + ((size_t)g * 64 + lane) * 8) =
                    *(const uint4*)&sc[(mb * 16 + l16) * 136 + kc * 32 + quad * 8];
            }
        } else {
            unsigned short* dst = vt + ((size_t)(bb * 32 + t)) * 16384;
            #pragma unroll
            for (int pi = 0; pi < 8; ++pi) {
                const int d  = pi * 256 + tid;
                const int cb = d >> 8, wq = (d >> 4) & 15, l = d & 15;
                *(uint4*)(dst + (size_t)d * 8) =
                    *(const uint4*)&sc[(cb * 16 + l) * 136 + wq * 8];
            }
        }
    }
}

// ---------------------------------------------------------------------------
// Kernel 2: attention. grid 256 = (b = bid&7, 128-row n-strip = bid>>3).
// 512 thr / 8 waves: m-half (w&1) x n-quarter (w>>1), W=2 (n=32/wave).
// 64 subiters of 64 m: K via double-buffered LDS DMA; V via L2->register
// ping-pong (vfA/vfB) with loads issued right after each barrier.
// ---------------------------------------------------------------------------
#define DMAK(TILE, BUFOFF) { \
    const unsigned short* ks_ = kb0 + (size_t)(TILE) * 8192; \
    _Pragma("unroll") \
    for (int i_ = 0; i_ < 2; ++i_) { \
        const int u_ = i_ * 512 + tid; \
        __builtin_amdgcn_global_load_lds((gbl_v*)(ks_ + (size_t)u_ * 8), \
                                         (lds_v*)(kbuf + (BUFOFF) + u_ * 8), 16, 0, 0); \
    } \
}

#define LOADV(VF, TILE) { \
    const unsigned short* vp_ = vb0 + (size_t)((TILE) >> 1) * 16384 \
        + (size_t)((((TILE) & 1) * 8 + mh * 4)) * 128 + (size_t)lane * 8; \
    _Pragma("unroll") \
    for (int cb_ = 0; cb_ < 8; ++cb_) \
        VF[cb_] = *(const v8bf*)(vp_ + cb_ * 2048); \
}

#define COMPUTE(BUFOFF, VF) { \
    const unsigned short* kp_ = kbuf + (BUFOFF); \
    v4f sacc_[2][2]; \
    sacc_[0][0] = (v4f){0.f,0.f,0.f,0.f}; sacc_[0][1] = (v4f){0.f,0.f,0.f,0.f}; \
    sacc_[1][0] = (v4f){0.f,0.f,0.f,0.f}; sacc_[1][1] = (v4f){0.f,0.f,0.f,0.f}; \
    _Pragma("unroll") \
    for (int mi_ = 0; mi_ < 2; ++mi_) \
        _Pragma("unroll") \
        for (int kc_ = 0; kc_ < 4; ++kc_) { \
            v8bf a_ = *(const v8bf*)(kp_ + ((mh * 2 + mi_) * 4 + kc_) * 512 + lane * 8); \
            sacc_[mi_][0] = __builtin_amdgcn_mfma_f32_16x16x32_bf16(a_, qf[0][kc_], sacc_[mi_][0], 0, 0, 0); \
            sacc_[mi_][1] = __builtin_amdgcn_mfma_f32_16x16x32_bf16(a_, qf[1][kc_], sacc_[mi_][1], 0, 0, 0); \
        } \
    unsigned pk_[2][2][2]; \
    _Pragma("unroll") \
    for (int mi_ = 0; mi_ < 2; ++mi_) \
        _Pragma("unroll") \
        for (int ni_ = 0; ni_ < 2; ++ni_) { \
            float e0 = __expf(sacc_[mi_][ni_][0]), e1 = __expf(sacc_[mi_][ni_][1]); \
            float e2 = __expf(sacc_[mi_][ni_][2]), e3 = __expf(sacc_[mi_][ni_][3]); \
            lpart[ni_] += (e0 + e1) + (e2 + e3); \
            pk_[mi_][ni_][0] = __builtin_amdgcn_perm(fbits(e1), fbits(e0), 0x07060302); \
            pk_[mi_][ni_][1] = __builtin_amdgcn_perm(fbits(e3), fbits(e2), 0x07060302); \
        } \
    v8bf pf_[2]; \
    _Pragma("unroll") \
    for (int ni_ = 0; ni_ < 2; ++ni_) { \
        unsigned sLo = (quad < 2) ? pk_[0][ni_][0] : pk_[1][ni_][0]; \
        unsigned sHi = (quad < 2) ? pk_[0][ni_][1] : pk_[1][ni_][1]; \
        union { unsigned u[4]; v8bf v; } pu; \
        pu.u[0] = (unsigned)__builtin_amdgcn_ds_bpermute(la, (int)sLo); \
        pu.u[1] = (unsigned)__builtin_amdgcn_ds_bpermute(la, (int)sHi); \
        pu.u[2] = (unsigned)__builtin_amdgcn_ds_bpermute(lb, (int)sLo); \
        pu.u[3] = (unsigned)__builtin_amdgcn_ds_bpermute(lb, (int)sHi); \
        pf_[ni_] = pu.v; \
    } \
    _Pragma("unroll") \
    for (int cb_ = 0; cb_ < 8; ++cb_) { \
        v8bf vv_ = VF[cb_]; \
        oacc[cb_][0] = __builtin_amdgcn_mfma_f32_16x16x32_bf16(vv_, pf_[0], oacc[cb_][0], 0, 0, 0); \
        oacc[cb_][1] = __builtin_amdgcn_mfma_f32_16x16x32_bf16(vv_, pf_[1], oacc[cb_][1], 0, 0, 0); \
    } \
}

__global__ __launch_bounds__(512, 2) void attn_kernel(
    const unsigned short* __restrict__ qf_ws, const unsigned short* __restrict__ kt,
    const unsigned short* __restrict__ vt, const float* __restrict__ x,
    const float* __restrict__ gamma, float* __restrict__ out)
{
    __shared__ __align__(16) unsigned char smem[68096]; // kbuf 32KB | red 128*133*4 overlay
    __shared__ float l_s[2][128];

    const int bid = blockIdx.x;
    const int bb  = bid & 7;
    const int s   = bid >> 3;        // 128-row n-strip 0..31
    const int n0  = s * 128;
    const int tid = threadIdx.x;
    const int w    = tid >> 6;
    const int lane = tid & 63;
    const int quad = lane >> 4;
    const int l16  = lane & 15;
    const int mh   = w & 1;          // m-half within 64-m subtile
    const int nq   = w >> 1;         // n-quarter 0..3 (32 rows each)

    // ---- Q fragments (n=32 window), iteration-invariant: 32 VGPR
    v8bf qf[2][4];
    {
        const unsigned short* qb = qf_ws + ((size_t)(bb * 128 + s * 4 + nq)) * 4096;
        #pragma unroll
        for (int ni = 0; ni < 2; ++ni)
            #pragma unroll
            for (int kc = 0; kc < 4; ++kc)
                qf[ni][kc] = *(const v8bf*)(qb + ((size_t)((ni * 4 + kc) * 64 + lane)) * 8);
    }

    v4f oacc[8][2];   // 64 regs (AGPR): partial O over this wave's m-half
    #pragma unroll
    for (int i = 0; i < 8; ++i) {
        oacc[i][0] = (v4f){0.f, 0.f, 0.f, 0.f};
        oacc[i][1] = (v4f){0.f, 0.f, 0.f, 0.f};
    }
    float lpart[2] = {0.f, 0.f};

    const int la = ((((quad & 1) << 1) << 4) + l16) << 2;  // bpermute byte idx
    const int lb = la + 64;

    const unsigned short* kb0 = kt + (size_t)bb * 524288;
    const unsigned short* vb0 = vt + (size_t)bb * 524288;
    unsigned short* kbuf = (unsigned short*)smem;   // [2][8192] elems

    v8bf vfA[8], vfB[8];

    DMAK(0, 0)
    LOADV(vfA, 0)

    for (int sp = 0; sp < 64; sp += 2) {
        __syncthreads();            // buf0 DMA drained; buf1 readers (sp-1) done
        DMAK(sp + 1, 8192)
        LOADV(vfB, sp + 1)          // in flight across this compute; drained next sync
        COMPUTE(0, vfA)
        __syncthreads();            // buf1 DMA drained; buf0 readers (sp) done
        if (sp < 62) DMAK(sp + 2, 0)
        LOADV(vfA, (sp + 2) & 63)
        COMPUTE(8192, vfB)
    }

    // ---- softmax denominators: per-wave partial over its m-half
    #pragma unroll
    for (int ni = 0; ni < 2; ++ni) {
        float r = lpart[ni];
        r += __shfl_xor(r, 16);
        r += __shfl_xor(r, 32);
        if (lane < 16) l_s[mh][nq * 32 + ni * 16 + lane] = r;
    }
    __syncthreads();   // main loop + l_s done; smem reusable

    // ---- O reduction across the 2 m-half waves per n-quarter: red[128][133]
    float* red = (float*)smem;
    #pragma unroll
    for (int ph = 0; ph < 2; ++ph) {
        if (mh == ph) {
            #pragma unroll
            for (int cb = 0; cb < 8; ++cb)
                #pragma unroll
                for (int ni = 0; ni < 2; ++ni) {
                    float* p = &red[(nq * 32 + ni * 16 + l16) * 133 + cb * 16 + quad * 4];
                    if (ph == 0) *(v4f*)p = oacc[cb][ni];
                    else {
                        v4f tv = *(const v4f*)p;
                        tv += oacc[cb][ni];
                        *(v4f*)p = tv;
                    }
                }
        }
        __syncthreads();
    }

    // ---- epilogue: out = gamma * O / l + x   (n = tid&127, coalesced)
    const float g = gamma[0];
    const int   n = tid & 127;
    const int  cg = tid >> 7;        // 0..3
    const float li = 1.0f / (l_s[0][n] + l_s[1][n]);
    #pragma unroll
    for (int j = 0; j < 32; ++j) {
        const int c = cg * 32 + j;
        const size_t idx = ((size_t)(bb * C_ + c)) * N_ + n0 + n;
        out[idx] = g * red[n * 133 + c] * li + x[idx];
    }
}

// ---------------------------------------------------------------------------
extern "C" void kernel_launch(void* const* d_in, const int* in_sizes, int n_in,
                              void* d_out, int out_size, void* d_ws, size_t ws_size,
                              hipStream_t stream)
{
    (void)in_sizes; (void)n_in; (void)out_size; (void)ws_size;
    const float* x     = (const float*)d_in[0];
    const float* dw_q  = (const float*)d_in[1];
    const float* pw_q  = (const float*)d_in[2];
    const float* dw_k  = (const float*)d_in[3];
    const float* pw_k  = (const float*)d_in[4];
    const float* dw_v  = (const float*)d_in[5];
    const float* pw_v  = (const float*)d_in[6];
    const float* gamma = (const float*)d_in[7];
    float* out = (float*)d_out;

    unsigned short* qf_ws = (unsigned short*)d_ws;                  // 8 MB
    unsigned short* kt    = qf_ws + (size_t)B_ * N_ * C_;           // 8 MB
    unsigned short* vt    = kt    + (size_t)B_ * N_ * C_;           // 8 MB

    proj_kernel<<<dim3(256), dim3(256), 0, stream>>>(
        x, dw_q, pw_q, dw_k, pw_k, dw_v, pw_v, qf_ws, kt, vt);
    attn_kernel<<<dim3(256), dim3(512), 0, stream>>>(
        qf_ws, kt, vt, x, gamma, out);
}

// Round 9
// 183.987 us; speedup vs baseline: 1.0481x; 1.0331x over previous
//
#include <hip/hip_runtime.h>
#include <hip/hip_bf16.h>

// PAM module R9: q/k/v 1x1 projections -> bf16 MFMA attention -> gamma*out + x.
// R8 post-mortem: pipes fully serialized (MFMA 1242 + VALU 1030 + LDS 900 ~= 3885
// measured cyc/subiter); true chip MFMA floor is ~33us (4x mis-scale fixed).
// R9: (1) 32x32x16 MFMA = 2x FLOP per operand byte; per-wave n=64 gives each
// K/V frag 2 MFMAs -> LDS pipe (2048) < MFMA pipe (2066) per 128-m subiter.
// (2) 160KB LDS: K AND V double-buffered at 128-m granularity (128KB), ONE
// barrier/subiter, DMA issued post-barrier (drain covered by ~2000-cyc compute).
// 512 thr / 8 waves = 4 m-quarters x 2 n-halves; P stays in registers via a
// cross-half (lane^32) bpermute transform derived for the 32x32 C/D layout.
//
// 32x32x16 layouts (m74/m101 C/D + scaled m89 A/B pattern):
//   A[i][k]: i = lane&31, k = (lane>>5)*8 + e   (8 bf16 / 4 VGPR)
//   B[k][j]: j = lane&31, k = (lane>>5)*8 + e
//   C/D:     col = lane&31, row = (reg&3) + 8*(reg>>2) + 4*(lane>>5)
//
// Workspace (bf16, frag-major, chunk = 64 lanes x 16B):
//   qf_ws[b][strip64][ni2][kc8][lane]{8}   8MB   Q[n=strip*64+ni*32+(l&31)][c=kc*16+(l>>5)*8+e]
//   kt   [b][sub64][mh2][kc8][lane]{8}     8MB   K[m=sub*64+mh*32+(l&31)][c=kc*16+(l>>5)*8+e]
//   vt   [b][sub64][cb4][km4][lane]{8}     8MB   V[c=cb*32+(l&31)][m=sub*64+km*16+(l>>5)*8+e]

typedef __bf16 v8bf __attribute__((ext_vector_type(8)));
typedef float  v4f  __attribute__((ext_vector_type(4)));
typedef float  v16f __attribute__((ext_vector_type(16)));
typedef __attribute__((address_space(3))) void       lds_v;
typedef const __attribute__((address_space(1))) void gbl_v;

#define B_ 8
#define C_ 128
#define N_ 4096

static __device__ __forceinline__ unsigned short f2bf_rne(float f) {
    union { float f; unsigned u; } v; v.f = f;
    return (unsigned short)((v.u + 0x7fffu + ((v.u >> 16) & 1u)) >> 16);
}
static __device__ __forceinline__ unsigned fbits(float f) {
    union { float f; unsigned u; } v; v.f = f; return v.u;
}

// ---------------------------------------------------------------------------
// Kernel 1: one block per (b, tile128). 256 thr / 4 waves. x staged once,
// 3 weight GEMMs (16x16 MFMA internals unchanged); NEW frag-major scatter for
// the 32x32 attention fragment layouts.
// ---------------------------------------------------------------------------
__global__ __launch_bounds__(256, 2) void proj_kernel(
    const float* __restrict__ x,
    const float* __restrict__ dw_q, const float* __restrict__ pw_q,
    const float* __restrict__ dw_k, const float* __restrict__ pw_k,
    const float* __restrict__ dw_v, const float* __restrict__ pw_v,
    unsigned short* __restrict__ qf_ws, unsigned short* __restrict__ kt,
    unsigned short* __restrict__ vt)
{
    __shared__ unsigned short xT[128 * 136];  // xT[n][c]
    __shared__ unsigned short Ws[128 * 136];  // W[o][c]; reused as store scratch

    const int bid = blockIdx.x;
    const int bb  = bid & 7;
    const int t   = bid >> 3;            // 0..31
    const int n0  = t * 128;
    const int tid = threadIdx.x;
    const int w    = tid >> 6;
    const int lane = tid & 63;
    const int quad = lane >> 4;
    const int l16  = lane & 15;

    #pragma unroll
    for (int k = 0; k < 16; ++k) {
        const int idx = tid + k * 256;
        const int c  = idx >> 5;
        const int nq = idx & 31;
        float4 f = *(const float4*)(x + ((size_t)(bb * C_ + c)) * N_ + n0 + nq * 4);
        xT[(nq * 4 + 0) * 136 + c] = f2bf_rne(f.x);
        xT[(nq * 4 + 1) * 136 + c] = f2bf_rne(f.y);
        xT[(nq * 4 + 2) * 136 + c] = f2bf_rne(f.z);
        xT[(nq * 4 + 3) * 136 + c] = f2bf_rne(f.w);
    }

    for (int pp = 0; pp < 3; ++pp) {
        __syncthreads();

        const float* pw = (pp == 0) ? pw_q : (pp == 1) ? pw_k : pw_v;
        const float* dw = (pp == 0) ? dw_q : (pp == 1) ? dw_k : dw_v;
        #pragma unroll
        for (int k = 0; k < 16; ++k) {
            const int idx = tid + k * 256;
            const int o  = idx >> 5;
            const int c4 = (idx & 31) * 4;
            float4 p4 = *(const float4*)(pw + o * 128 + c4);
            float4 d4 = *(const float4*)(dw + c4);
            unsigned lo = (unsigned)f2bf_rne(p4.x * d4.x) | ((unsigned)f2bf_rne(p4.y * d4.y) << 16);
            unsigned hi = (unsigned)f2bf_rne(p4.z * d4.z) | ((unsigned)f2bf_rne(p4.w * d4.w) << 16);
            *(unsigned long long*)&Ws[o * 136 + c4] =
                (unsigned long long)lo | ((unsigned long long)hi << 32);
        }
        __syncthreads();

        const unsigned short* As = (pp < 2) ? xT : Ws;
        const unsigned short* Bs = (pp < 2) ? Ws : xT;

        v4f acc[2][8];
        #pragma unroll
        for (int i = 0; i < 2; ++i)
            #pragma unroll
            for (int j = 0; j < 8; ++j)
                acc[i][j] = (v4f){0.f, 0.f, 0.f, 0.f};

        #pragma unroll
        for (int kc = 0; kc < 4; ++kc) {
            v8bf av[2];
            #pragma unroll
            for (int i = 0; i < 2; ++i)
                av[i] = *(const v8bf*)&As[(w * 32 + i * 16 + l16) * 136 + kc * 32 + quad * 8];
            #pragma unroll
            for (int cb = 0; cb < 8; ++cb) {
                v8bf bv = *(const v8bf*)&Bs[(cb * 16 + l16) * 136 + kc * 32 + quad * 8];
                acc[0][cb] = __builtin_amdgcn_mfma_f32_16x16x32_bf16(av[0], bv, acc[0][cb], 0, 0, 0);
                acc[1][cb] = __builtin_amdgcn_mfma_f32_16x16x32_bf16(av[1], bv, acc[1][cb], 0, 0, 0);
            }
        }
        __syncthreads();   // done reading Ws; becomes scratch

        unsigned short* sc = Ws;   // sc[row 0..127][col 0..127], stride 136
        #pragma unroll
        for (int mi = 0; mi < 2; ++mi)
            #pragma unroll
            for (int cb = 0; cb < 8; ++cb)
                #pragma unroll
                for (int r = 0; r < 4; ++r)
                    sc[(w * 32 + mi * 16 + quad * 4 + r) * 136 + cb * 16 + l16] =
                        f2bf_rne(acc[mi][cb][r]);
        __syncthreads();

        // ---- frag-major scatter (2048 x 16B chunks, coalesced)
        if (pp == 0) {
            unsigned short* dst = qf_ws + ((size_t)(bb * 64 + t * 2)) * 8192;
            #pragma unroll
            for (int p = 0; p < 8; ++p) {
                const int u  = p * 256 + tid;
                const int lu = u & 63, kc = (u >> 6) & 7, ni = (u >> 9) & 1, st = u >> 10;
                const int row = st * 64 + ni * 32 + (lu & 31);
                const int col = kc * 16 + (lu >> 5) * 8;
                *(uint4*)(dst + (size_t)u * 8) = *(const uint4*)&sc[row * 136 + col];
            }
        } else if (pp == 1) {
            unsigned short* dst = kt + ((size_t)(bb * 64 + t * 2)) * 8192;
            #pragma unroll
            for (int p = 0; p < 8; ++p) {
                const int u  = p * 256 + tid;
                const int lu = u & 63, kc = (u >> 6) & 7, mh = (u >> 9) & 1, st = u >> 10;
                const int row = st * 64 + mh * 32 + (lu & 31);
                const int col = kc * 16 + (lu >> 5) * 8;
                *(uint4*)(dst + (size_t)u * 8) = *(const uint4*)&sc[row * 136 + col];
            }
        } else {
            unsigned short* dst = vt + ((size_t)(bb * 64 + t * 2)) * 8192;
            #pragma unroll
            for (int p = 0; p < 8; ++p) {
                const int u  = p * 256 + tid;
                const int lu = u & 63, km = (u >> 6) & 3, cb = (u >> 8) & 3, st = u >> 10;
                const int row = cb * 32 + (lu & 31);                 // c
                const int col = st * 64 + km * 16 + (lu >> 5) * 8;   // m
                *(uint4*)(dst + (size_t)u * 8) = *(const uint4*)&sc[row * 136 + col];
            }
        }
    }
}

// ---------------------------------------------------------------------------
// Kernel 2: attention. grid 256 = (b = bid&7, 128-n strip = bid>>3). 512 thr /
// 8 waves = 4 mq (32 m of the 128-m subiter) x 2 nh (64 n). 32 subiters:
//   sync; DMA(next 128-m K+V -> other 64KB buf); S (32x32, Q reg-resident);
//   exp; cross-half bpermute -> P B-frags; PV.
// ---------------------------------------------------------------------------
__global__ __launch_bounds__(512, 2) void attn_kernel(
    const unsigned short* __restrict__ qf_ws, const unsigned short* __restrict__ kt,
    const unsigned short* __restrict__ vt, const float* __restrict__ x,
    const float* __restrict__ gamma, float* __restrict__ out)
{
    __shared__ __align__(16) unsigned char smem[131072]; // kbuf 2x32K | vbuf 2x32K; red overlays
    __shared__ float l_s[4][128];

    const int bid = blockIdx.x;
    const int bb  = bid & 7;
    const int s   = bid >> 3;        // 128-n strip 0..31
    const int tid = threadIdx.x;
    const int w    = tid >> 6;
    const int lane = tid & 63;
    const int h    = lane >> 5;      // lane half
    const int l31  = lane & 31;
    const int mq   = w & 3;          // m-quarter (32 m) of 128-m subiter
    const int nh   = w >> 2;         // n-half (64 n)

    // ---- Q fragments (B-operand), iteration-invariant: 64 VGPR
    v8bf qf[2][8];
    {
        const unsigned short* qb = qf_ws + ((size_t)(bb * 64 + s * 2 + nh)) * 8192;
        #pragma unroll
        for (int ni = 0; ni < 2; ++ni)
            #pragma unroll
            for (int kc = 0; kc < 8; ++kc)
                qf[ni][kc] = *(const v8bf*)(qb + ((size_t)((ni * 8 + kc) * 64 + lane)) * 8);
    }

    v16f oacc[4][2];   // [cb][ni]: O[c=cb*32+..][n=nh*64+ni*32+..], 128 AGPR
    #pragma unroll
    for (int i = 0; i < 4; ++i)
        #pragma unroll
        for (int j = 0; j < 2; ++j)
            #pragma unroll
            for (int r = 0; r < 16; ++r)
                oacc[i][j][r] = 0.f;
    float lpart[2] = {0.f, 0.f};

    const int xlane = (lane ^ 32) << 2;   // bpermute byte idx: cross-half partner

    const unsigned short* ktb = kt + (size_t)bb * 524288;
    const unsigned short* vtb = vt + (size_t)bb * 524288;
    unsigned short* kbuf = (unsigned short*)smem;            // [2][16384] elems
    unsigned short* vbuf = (unsigned short*)(smem + 65536);  // [2][16384] elems

    // ---- prologue: DMA subiter 0 (subtiles 0,1 = 32KB K + 32KB V) into buf 0
    #pragma unroll
    for (int i = 0; i < 4; ++i) {
        const int u = i * 512 + tid;
        __builtin_amdgcn_global_load_lds((gbl_v*)(ktb + (size_t)u * 8),
                                         (lds_v*)(kbuf + u * 8), 16, 0, 0);
        __builtin_amdgcn_global_load_lds((gbl_v*)(vtb + (size_t)u * 8),
                                         (lds_v*)(vbuf + u * 8), 16, 0, 0);
    }

    for (int si = 0; si < 32; ++si) {
        __syncthreads();   // DMA(si) drained (vmcnt) + prior readers of other buf done

        if (si < 31) {
            const int p = (si + 1) & 1;
            const unsigned short* ks = ktb + (size_t)(si + 1) * 16384;
            const unsigned short* vs = vtb + (size_t)(si + 1) * 16384;
            #pragma unroll
            for (int i = 0; i < 4; ++i) {
                const int u = i * 512 + tid;
                __builtin_amdgcn_global_load_lds((gbl_v*)(ks + (size_t)u * 8),
                                                 (lds_v*)(kbuf + p * 16384 + u * 8), 16, 0, 0);
                __builtin_amdgcn_global_load_lds((gbl_v*)(vs + (size_t)u * 8),
                                                 (lds_v*)(vbuf + p * 16384 + u * 8), 16, 0, 0);
            }
        }

        const unsigned short* kpb = kbuf + (si & 1) * 16384 + mq * 4096 + lane * 8;
        const unsigned short* vpb = vbuf + (si & 1) * 16384
                                    + ((mq >> 1) * 16 + (mq & 1) * 2) * 512 + lane * 8;

        // ---- S^T: wave's 32 m x 64 n  (A = K rows m, B = Q cols n)
        v16f sa0, sa1;
        #pragma unroll
        for (int r = 0; r < 16; ++r) { sa0[r] = 0.f; sa1[r] = 0.f; }
        #pragma unroll
        for (int kc = 0; kc < 8; ++kc) {
            v8bf kf = *(const v8bf*)(kpb + kc * 512);
            sa0 = __builtin_amdgcn_mfma_f32_32x32x16_bf16(kf, qf[0][kc], sa0, 0, 0, 0);
            sa1 = __builtin_amdgcn_mfma_f32_32x32x16_bf16(kf, qf[1][kc], sa1, 0, 0, 0);
        }

        // ---- exp + pack pairs (m ascending within reg-groups g: regs 4g..4g+3)
        unsigned pk[2][4][2];
        #pragma unroll
        for (int ni = 0; ni < 2; ++ni) {
            float e[16];
            #pragma unroll
            for (int r = 0; r < 16; ++r) {
                e[r] = __expf(ni ? sa1[r] : sa0[r]);
                lpart[ni] += e[r];
            }
            #pragma unroll
            for (int g = 0; g < 4; ++g) {
                pk[ni][g][0] = __builtin_amdgcn_perm(fbits(e[4 * g + 1]), fbits(e[4 * g + 0]), 0x07060302);
                pk[ni][g][1] = __builtin_amdgcn_perm(fbits(e[4 * g + 3]), fbits(e[4 * g + 2]), 0x07060302);
            }
        }

        // ---- per km: C-layout -> B-frag. Own group g = km*2+h (m-pairs it keeps),
        // send group g = km*2+(1-h) (what the partner half needs); cross-half via
        // bpermute(lane^32). Frag order: h==0 -> [own,own,x,x], h==1 -> [x,x,own,own].
        #pragma unroll
        for (int km = 0; km < 2; ++km) {
            v8bf pf[2];
            #pragma unroll
            for (int ni = 0; ni < 2; ++ni) {
                unsigned aO = h ? pk[ni][km * 2 + 1][0] : pk[ni][km * 2][0];
                unsigned bO = h ? pk[ni][km * 2 + 1][1] : pk[ni][km * 2][1];
                unsigned aS = h ? pk[ni][km * 2][0]     : pk[ni][km * 2 + 1][0];
                unsigned bS = h ? pk[ni][km * 2][1]     : pk[ni][km * 2 + 1][1];
                unsigned xa = (unsigned)__builtin_amdgcn_ds_bpermute(xlane, (int)aS);
                unsigned xb = (unsigned)__builtin_amdgcn_ds_bpermute(xlane, (int)bS);
                union { unsigned u[4]; v8bf v; } pu;
                pu.u[0] = h ? xa : aO;
                pu.u[1] = h ? xb : bO;
                pu.u[2] = h ? aO : xa;
                pu.u[3] = h ? bO : xb;
                pf[ni] = pu.v;
            }
            // ---- PV: O[c][n] += V * P  (A = V rows c, contraction = 16 m)
            #pragma unroll
            for (int cb = 0; cb < 4; ++cb) {
                v8bf vf = *(const v8bf*)(vpb + (cb * 4 + km) * 512);
                oacc[cb][0] = __builtin_amdgcn_mfma_f32_32x32x16_bf16(vf, pf[0], oacc[cb][0], 0, 0, 0);
                oacc[cb][1] = __builtin_amdgcn_mfma_f32_32x32x16_bf16(vf, pf[1], oacc[cb][1], 0, 0, 0);
            }
        }
    }

    // ---- softmax denominators: sum over wave's 32 m (16/lane + partner half)
    #pragma unroll
    for (int ni = 0; ni < 2; ++ni) {
        float r = lpart[ni] + __shfl_xor(lpart[ni], 32);
        if (h == 0) l_s[mq][nh * 64 + ni * 32 + l31] = r;
    }
    __syncthreads();   // main loop + l_s done; smem reusable

    // ---- O reduction across the 4 mq waves: red[n 128][c 128] stride 133
    float* red = (float*)smem;
    for (int ph = 0; ph < 4; ++ph) {
        if (mq == ph) {
            #pragma unroll
            for (int cb = 0; cb < 4; ++cb)
                #pragma unroll
                for (int ni = 0; ni < 2; ++ni)
                    #pragma unroll
                    for (int g = 0; g < 4; ++g) {
                        float* p = &red[(nh * 64 + ni * 32 + l31) * 133 + cb * 32 + g * 8 + h * 4];
                        v4f val = {oacc[cb][ni][4 * g + 0], oacc[cb][ni][4 * g + 1],
                                   oacc[cb][ni][4 * g + 2], oacc[cb][ni][4 * g + 3]};
                        if (ph == 0) *(v4f*)p = val;
                        else {
                            v4f tv = *(const v4f*)p;
                            tv += val;
                            *(v4f*)p = tv;
                        }
                    }
        }
        __syncthreads();
    }

    // ---- epilogue: out = gamma * O / l + x   (n = tid&127, coalesced)
    const float g = gamma[0];
    const int   n = tid & 127;
    const int  cg = tid >> 7;        // 0..3
    const float li = 1.0f / ((l_s[0][n] + l_s[1][n]) + (l_s[2][n] + l_s[3][n]));
    #pragma unroll
    for (int j = 0; j < 32; ++j) {
        const int c = cg * 32 + j;
        const size_t idx = ((size_t)(bb * C_ + c)) * N_ + s * 128 + n;
        out[idx] = g * red[n * 133 + c] * li + x[idx];
    }
}

// ---------------------------------------------------------------------------
extern "C" void kernel_launch(void* const* d_in, const int* in_sizes, int n_in,
                              void* d_out, int out_size, void* d_ws, size_t ws_size,
                              hipStream_t stream)
{
    (void)in_sizes; (void)n_in; (void)out_size; (void)ws_size;
    const float* x     = (const float*)d_in[0];
    const float* dw_q  = (const float*)d_in[1];
    const float* pw_q  = (const float*)d_in[2];
    const float* dw_k  = (const float*)d_in[3];
    const float* pw_k  = (const float*)d_in[4];
    const float* dw_v  = (const float*)d_in[5];
    const float* pw_v  = (const float*)d_in[6];
    const float* gamma = (const float*)d_in[7];
    float* out = (float*)d_out;

    unsigned short* qf_ws = (unsigned short*)d_ws;                  // 8 MB
    unsigned short* kt    = qf_ws + (size_t)B_ * N_ * C_;           // 8 MB
    unsigned short* vt    = kt    + (size_t)B_ * N_ * C_;           // 8 MB

    proj_kernel<<<dim3(256), dim3(256), 0, stream>>>(
        x, dw_q, pw_q, dw_k, pw_k, dw_v, pw_v, qf_ws, kt, vt);
    attn_kernel<<<dim3(256), dim3(512), 0, stream>>>(
        qf_ws, kt, vt, x, gamma, out);
}